// Round 5
// baseline (3574.094 us; speedup 1.0000x reference)
//
#include <hip/hip_runtime.h>
#include <cstddef>

#define TT 16384
#define NBATCH 8
#define CH 128        // padded residual channels
#define RES 120
#define SKIPC 240
#define NQ 256
#define NT2 32        // timesteps per workgroup (fast path)
#define NTF 64        // timesteps per workgroup (fallback path)
#define KZ 2048       // 16 layers * 128 ch, head skip-GEMM K

typedef __attribute__((ext_vector_type(8))) short bf8;   // 8 bf16 (4 VGPR)
typedef __attribute__((ext_vector_type(4))) short s4;    // 4 bf16 (8B)
typedef __attribute__((ext_vector_type(4))) float f32x4;

__device__ __forceinline__ short f2bf(float f) {
  unsigned u = __builtin_bit_cast(unsigned, f);
  u += 0x7fffu + ((u >> 16) & 1u);
  return (short)(u >> 16);
}
__device__ __forceinline__ float bf2f(short s) {
  unsigned u = ((unsigned)(unsigned short)s) << 16;
  return __builtin_bit_cast(float, u);
}

// ---- pack all weights to bf16, padded, MFMA row-major [M][K] ----
__global__ void k_pack(const float* __restrict__ Wf, const float* __restrict__ Wg,
                       const float* __restrict__ Wres, const float* __restrict__ Wskip,
                       const float* __restrict__ W1, const float* __restrict__ W2,
                       const float* __restrict__ bf, const float* __restrict__ bg,
                       const float* __restrict__ bres, const float* __restrict__ bskip,
                       short* __restrict__ Afg, short* __restrict__ Ars,
                       short* __restrict__ W1p, short* __restrict__ W2p,
                       float* __restrict__ biasp,
                       short* __restrict__ Wskp, float* __restrict__ bsum, int do2) {
  const int NAFG = 16 * 256 * 256;   // 1048576
  const int NARS = 16 * 384 * 128;   // 786432
  const int NW = 256 * 256;          // 65536
  const int NBIA = 16 * (128 * 3 + 256);
  const int NWSK = 256 * 2048;
  const int total = NAFG + NARS + 2 * NW + NBIA + NWSK + 256;
  for (int idx = blockIdx.x * blockDim.x + threadIdx.x; idx < total;
       idx += gridDim.x * blockDim.x) {
    if (idx < NAFG) {
      int i = idx >> 16, rem = idx & 65535, m = rem >> 8, k = rem & 255;
      int tap = k >> 7, ci = k & 127;
      float v = 0.f;
      if (ci < 120) {
        if (m < 120) v = Wf[((i * 120 + m) * 120 + ci) * 2 + tap];
        else if (m >= 128 && m < 248) v = Wg[((i * 120 + (m - 128)) * 120 + ci) * 2 + tap];
      }
      Afg[idx] = f2bf(v);
    } else if (idx < NAFG + NARS) {
      int j = idx - NAFG;
      int i = j / 49152, rem = j % 49152, m = rem >> 7, k = rem & 127;
      float v = 0.f;
      if (k < 120) {
        if (m < 120) v = Wres[(i * 120 + m) * 120 + k];
        else if (m >= 128 && m < 368) v = Wskip[(i * 240 + (m - 128)) * 120 + k];
      }
      Ars[j] = f2bf(v);
    } else if (idx < NAFG + NARS + NW) {
      int j = idx - NAFG - NARS, q = j >> 8, k = j & 255;
      W1p[j] = f2bf(k < 240 ? W1[q * 240 + k] : 0.f);
    } else if (idx < NAFG + NARS + 2 * NW) {
      int j = idx - NAFG - NARS - NW;
      W2p[j] = f2bf(W2[j]);
    } else if (idx < NAFG + NARS + 2 * NW + NBIA) {
      int j = idx - NAFG - NARS - 2 * NW;
      float v = 0.f;
      if (j < 2048) { int i = j >> 7, c = j & 127; if (c < 120) v = bf[i * 120 + c]; }
      else if (j < 4096) { int jj = j - 2048; int i = jj >> 7, c = jj & 127; if (c < 120) v = bg[i * 120 + c]; }
      else if (j < 6144) { int jj = j - 4096; int i = jj >> 7, c = jj & 127; if (c < 120) v = bres[i * 120 + c]; }
      else { int jj = j - 6144; int i = jj >> 8, c = jj & 255; if (c < 240) v = bskip[i * 240 + c]; }
      biasp[j] = v;
    } else if (idx < NAFG + NARS + 2 * NW + NBIA + NWSK) {
      if (do2) {
        int j = idx - NAFG - NARS - 2 * NW - NBIA;
        int m = j >> 11, k = j & 2047;
        int layer = k >> 7, ci = k & 127;
        float v = 0.f;
        if (m < 240 && ci < 120) v = Wskip[((size_t)layer * 240 + m) * 120 + ci];
        Wskp[j] = f2bf(v);
      }
    } else {
      if (do2) {
        int m = idx - (NAFG + NARS + 2 * NW + NBIA + NWSK);
        float v = 0.f;
        if (m < 240)
          for (int l = 0; l < 16; l++) v += bskip[l * 240 + m];
        bsum[m] = v;
      }
    }
  }
}

// x0[b][t][c] = bf16(W_in[c]*wave[b][t] + b_in[c]), pad channels zero
__global__ void k_input(const float* __restrict__ wave, const float* __restrict__ win,
                        const float* __restrict__ bin, short* __restrict__ x0) {
  int idx = blockIdx.x * blockDim.x + threadIdx.x;  // one per (b,t)
  if (idx >= NBATCH * TT) return;
  float wv = wave[idx];
  short* row = x0 + (size_t)idx * CH;
  for (int c = 0; c < CH; c += 4) {
    s4 v;
#pragma unroll
    for (int j = 0; j < 4; j++)
      v[j] = (c + j < 120) ? f2bf(win[c + j] * wv + bin[c + j]) : (short)0;
    *(s4*)(row + c) = v;
  }
}

// ================== zg PATH: residual block (512 thr, NT2=32) ==================
__global__ __launch_bounds__(512) void k_res2(
    const short* __restrict__ xin, short* __restrict__ xout,
    short* __restrict__ zg,
    const short* __restrict__ Afg, const short* __restrict__ Ars,
    const float* __restrict__ biasp, int layer, int dil, int b_off) {
  __shared__ short zT[NT2][136];
  const int bl = blockIdx.y;          // group-local batch
  const int b = b_off + bl;           // global batch
  const int t0 = blockIdx.x * NT2;
  const int tid = threadIdx.x;
  const int lane = tid & 63, w = tid >> 6;   // w 0..7
  const int l15 = lane & 15, l4 = lane >> 4;
  const size_t xbase = (size_t)b * TT * CH;

  // ---------- fg GEMM: M=256 (f rows w*16, g rows 128+w*16), K=256, N=32 ----------
  f32x4 fa[2], ga[2];
  fa[0] = (f32x4)0.f; fa[1] = (f32x4)0.f; ga[0] = (f32x4)0.f; ga[1] = (f32x4)0.f;

  const short* pBd[2];
  const short* pBc[2];
  bool vld[2];
#pragma unroll
  for (int nt = 0; nt < 2; nt++) {
    int t = t0 + nt * 16 + l15;
    int ts = t - dil;
    vld[nt] = (ts >= 0);
    pBd[nt] = xin + xbase + (size_t)(vld[nt] ? ts : 0) * CH + l4 * 8;
    pBc[nt] = xin + xbase + (size_t)t * CH + l4 * 8;
  }
  const short* pAf = Afg + (size_t)(w * 16 + l15) * 256 + l4 * 8;
  const short* pAg = Afg + (size_t)(128 + w * 16 + l15) * 256 + l4 * 8;
  const bf8 zv = (bf8)(short)0;
#pragma unroll
  for (int kk = 0; kk < 8; kk++) {
    const int k = kk * 32;  // k<128: delayed tap, k>=128: current tap
    bf8 Bv[2];
#pragma unroll
    for (int nt = 0; nt < 2; nt++) {
      if (kk < 4) {
        bf8 v = *(const bf8*)(pBd[nt] + k);
        Bv[nt] = vld[nt] ? v : zv;
      } else {
        Bv[nt] = *(const bf8*)(pBc[nt] + (k - 128));
      }
    }
    bf8 Av = *(const bf8*)(pAf + k);
    bf8 Gv = *(const bf8*)(pAg + k);
#pragma unroll
    for (int nt = 0; nt < 2; nt++) {
      fa[nt] = __builtin_amdgcn_mfma_f32_16x16x32_bf16(Av, Bv[nt], fa[nt], 0, 0, 0);
      ga[nt] = __builtin_amdgcn_mfma_f32_16x16x32_bf16(Gv, Bv[nt], ga[nt], 0, 0, 0);
    }
  }

  // activation -> zT (transposed, [t][c]); this wave's channels: w*16 + l4*4 + r
  const float* bf_ = biasp + (size_t)layer * 128;
  const float* bg_ = biasp + 2048 + (size_t)layer * 128;
  const int mb = w * 16 + l4 * 4;
#pragma unroll
  for (int nt = 0; nt < 2; nt++) {
    s4 zp;
#pragma unroll
    for (int r = 0; r < 4; r++) {
      float f = fa[nt][r] + bf_[mb + r];
      float g = ga[nt][r] + bg_[mb + r];
      float th = 1.f - 2.f / (__expf(2.f * f) + 1.f);
      float sg = 1.f / (1.f + __expf(-g));
      zp[r] = f2bf(th * sg);
    }
    *(s4*)&zT[nt * 16 + l15][mb] = zp;
  }
  __syncthreads();

  // z write to global (nontemporal; consumed only by head much later)
  {
    const int u = tid;               // NT2*16 == 512 == blockDim
    const int t = u >> 4, c8 = u & 15;
    bf8 v = *(const bf8*)&zT[t][c8 * 8];
    __builtin_nontemporal_store(
        v, (bf8*)(zg + ((size_t)(bl * TT + t0 + t) * 16 + layer) * 128 + c8 * 8));
  }

  // ---------- res GEMM: M=128 (rows w*16), K=128, N=32 ----------
  f32x4 acc[2];
  acc[0] = (f32x4)0.f; acc[1] = (f32x4)0.f;
  const short* pA = Ars + (size_t)(w * 16 + l15) * 128 + l4 * 8;
#pragma unroll
  for (int kk = 0; kk < 4; kk++) {
    const int k = kk * 32;
    bf8 Bv[2];
#pragma unroll
    for (int nt = 0; nt < 2; nt++) Bv[nt] = *(const bf8*)&zT[nt * 16 + l15][k + l4 * 8];
    bf8 Av = *(const bf8*)(pA + k);
#pragma unroll
    for (int nt = 0; nt < 2; nt++)
      acc[nt] = __builtin_amdgcn_mfma_f32_16x16x32_bf16(Av, Bv[nt], acc[nt], 0, 0, 0);
  }

  const float* br_ = biasp + 4096 + (size_t)layer * 128;
  const int m = w * 16 + l4 * 4;
#pragma unroll
  for (int nt = 0; nt < 2; nt++) {
    int t = t0 + nt * 16 + l15;
    s4 xv = *(const s4*)(xin + xbase + (size_t)t * CH + m);
    s4 ov;
#pragma unroll
    for (int r = 0; r < 4; r++)
      ov[r] = f2bf(bf2f(xv[r]) + acc[nt][r] + br_[m + r]);
    *(s4*)(xout + xbase + (size_t)t * CH + m) = ov;
  }
}

// ====== zg PATH head (512 thr, NT2=32): skip GEMM K=2048 + relu + W1 + relu + W2 ======
__global__ __launch_bounds__(512) void k_head2(
    const short* __restrict__ zg, const short* __restrict__ Wskp,
    const float* __restrict__ bsum,
    const short* __restrict__ W1p, const float* __restrict__ b1,
    const short* __restrict__ W2p, const float* __restrict__ b2,
    float* __restrict__ out, int b_off) {
  __shared__ short hT[NT2][264];
  const int bl = blockIdx.y;
  const int b = b_off + bl;
  const int t0 = blockIdx.x * NT2;
  const int tid = threadIdx.x;
  const int lane = tid & 63, w = tid >> 6;   // w 0..7
  const int l15 = lane & 15, l4 = lane >> 4;

  f32x4 acc[2][2];
#pragma unroll
  for (int i = 0; i < 2; i++)
#pragma unroll
    for (int j = 0; j < 2; j++) acc[i][j] = (f32x4)0.f;

  // skip GEMM: M=256 (rows w*32+mt*16), K=2048, N=32, depth-2 rotating prefetch
  const short* pB0 = zg + (size_t)(bl * TT + t0 + l15) * KZ + l4 * 8;
  const short* pB1 = zg + (size_t)(bl * TT + t0 + 16 + l15) * KZ + l4 * 8;
  const short* pA0 = Wskp + (size_t)(w * 32 + l15) * KZ + l4 * 8;
  const short* pA1 = Wskp + (size_t)(w * 32 + 16 + l15) * KZ + l4 * 8;
  bf8 B0 = *(const bf8*)pB0, B1 = *(const bf8*)pB1;
  bf8 A0 = *(const bf8*)pA0, A1 = *(const bf8*)pA1;
  for (int kk = 0; kk < 64; kk++) {
    const int ko = ((kk + 1) & 63) * 32;   // wraps to 0 on last iter (harmless)
    bf8 nB0 = *(const bf8*)(pB0 + ko);
    bf8 nB1 = *(const bf8*)(pB1 + ko);
    bf8 nA0 = *(const bf8*)(pA0 + ko);
    bf8 nA1 = *(const bf8*)(pA1 + ko);
    acc[0][0] = __builtin_amdgcn_mfma_f32_16x16x32_bf16(A0, B0, acc[0][0], 0, 0, 0);
    acc[0][1] = __builtin_amdgcn_mfma_f32_16x16x32_bf16(A0, B1, acc[0][1], 0, 0, 0);
    acc[1][0] = __builtin_amdgcn_mfma_f32_16x16x32_bf16(A1, B0, acc[1][0], 0, 0, 0);
    acc[1][1] = __builtin_amdgcn_mfma_f32_16x16x32_bf16(A1, B1, acc[1][1], 0, 0, 0);
    B0 = nB0; B1 = nB1; A0 = nA0; A1 = nA1;
  }
  // h = relu(skip + bsum) -> hT
#pragma unroll
  for (int mt = 0; mt < 2; mt++) {
    int mb = w * 32 + mt * 16 + l4 * 4;
#pragma unroll
    for (int nt = 0; nt < 2; nt++) {
      s4 hp;
#pragma unroll
      for (int r = 0; r < 4; r++)
        hp[r] = f2bf(fmaxf(acc[mt][nt][r] + bsum[mb + r], 0.f));
      *(s4*)&hT[nt * 16 + l15][mb] = hp;
    }
  }
  __syncthreads();

  // GEMM1: W1p, M=256 K=256 N=32
#pragma unroll
  for (int i = 0; i < 2; i++)
#pragma unroll
    for (int j = 0; j < 2; j++) acc[i][j] = (f32x4)0.f;
#pragma unroll
  for (int kk = 0; kk < 8; kk++) {
    const int k = kk * 32;
    bf8 Bv[2];
#pragma unroll
    for (int nt = 0; nt < 2; nt++) Bv[nt] = *(const bf8*)&hT[nt * 16 + l15][k + l4 * 8];
#pragma unroll
    for (int mt = 0; mt < 2; mt++) {
      bf8 Av = *(const bf8*)(W1p + (size_t)(w * 32 + mt * 16 + l15) * 256 + k + l4 * 8);
#pragma unroll
      for (int nt = 0; nt < 2; nt++)
        acc[mt][nt] = __builtin_amdgcn_mfma_f32_16x16x32_bf16(Av, Bv[nt], acc[mt][nt], 0, 0, 0);
    }
  }
  __syncthreads();  // all reads of hT done
  // h1 = relu(acc + b1) -> hT (reused)
#pragma unroll
  for (int mt = 0; mt < 2; mt++) {
    int mb = w * 32 + mt * 16 + l4 * 4;
#pragma unroll
    for (int nt = 0; nt < 2; nt++) {
      s4 hp;
#pragma unroll
      for (int r = 0; r < 4; r++)
        hp[r] = f2bf(fmaxf(acc[mt][nt][r] + b1[mb + r], 0.f));
      *(s4*)&hT[nt * 16 + l15][mb] = hp;
    }
  }
  __syncthreads();

  // GEMM2: W2p, M=256 K=256 N=32
#pragma unroll
  for (int i = 0; i < 2; i++)
#pragma unroll
    for (int j = 0; j < 2; j++) acc[i][j] = (f32x4)0.f;
#pragma unroll
  for (int kk = 0; kk < 8; kk++) {
    const int k = kk * 32;
    bf8 Bv[2];
#pragma unroll
    for (int nt = 0; nt < 2; nt++) Bv[nt] = *(const bf8*)&hT[nt * 16 + l15][k + l4 * 8];
#pragma unroll
    for (int mt = 0; mt < 2; mt++) {
      bf8 Av = *(const bf8*)(W2p + (size_t)(w * 32 + mt * 16 + l15) * 256 + k + l4 * 8);
#pragma unroll
      for (int nt = 0; nt < 2; nt++)
        acc[mt][nt] = __builtin_amdgcn_mfma_f32_16x16x32_bf16(Av, Bv[nt], acc[mt][nt], 0, 0, 0);
    }
  }
#pragma unroll
  for (int mt = 0; mt < 2; mt++) {
    int q = w * 32 + mt * 16 + l4 * 4;
#pragma unroll
    for (int nt = 0; nt < 2; nt++) {
      int t = t0 + nt * 16 + l15;
#pragma unroll
      for (int r = 0; r < 4; r++) {
        float v = acc[mt][nt][r] + b2[q + r];
        __builtin_nontemporal_store(v, out + ((size_t)b * NQ + q + r) * TT + t);
      }
    }
  }
}

// ================== FALLBACK PATH (round-2, passing; NTF=64, 256 thr) ==================
__global__ __launch_bounds__(256) void k_res_mfma(
    const short* __restrict__ xin, short* __restrict__ xout,
    float* __restrict__ skip,
    const short* __restrict__ Afg, const short* __restrict__ Ars,
    const float* __restrict__ biasp, int layer, int dil, int first) {
  __shared__ short zT[NTF][136];
  const int b = blockIdx.y;
  const int t0 = blockIdx.x * NTF;
  const int tid = threadIdx.x;
  const int lane = tid & 63, w = tid >> 6;
  const int l15 = lane & 15, l4 = lane >> 4;
  const size_t xbase = (size_t)b * TT * CH;

  f32x4 fa[2][4], ga[2][4];
#pragma unroll
  for (int i = 0; i < 2; i++)
#pragma unroll
    for (int j = 0; j < 4; j++) { fa[i][j] = (f32x4)0.f; ga[i][j] = (f32x4)0.f; }

  const short* pBd[4];
  const short* pBc[4];
  bool vld[4];
#pragma unroll
  for (int nt = 0; nt < 4; nt++) {
    int t = t0 + nt * 16 + l15;
    int ts = t - dil;
    vld[nt] = (ts >= 0);
    pBd[nt] = xin + xbase + (size_t)(vld[nt] ? ts : 0) * CH + l4 * 8;
    pBc[nt] = xin + xbase + (size_t)t * CH + l4 * 8;
  }
  const short* pAf[2];
  const short* pAg[2];
#pragma unroll
  for (int mt = 0; mt < 2; mt++) {
    pAf[mt] = Afg + (size_t)(w * 32 + mt * 16 + l15) * 256 + l4 * 8;
    pAg[mt] = Afg + (size_t)(128 + w * 32 + mt * 16 + l15) * 256 + l4 * 8;
  }
  const bf8 zv = (bf8)(short)0;
#pragma unroll
  for (int kk = 0; kk < 8; kk++) {
    const int k = kk * 32;
    bf8 Bv[4];
#pragma unroll
    for (int nt = 0; nt < 4; nt++) {
      if (kk < 4) {
        bf8 v = *(const bf8*)(pBd[nt] + k);
        Bv[nt] = vld[nt] ? v : zv;
      } else {
        Bv[nt] = *(const bf8*)(pBc[nt] + (k - 128));
      }
    }
#pragma unroll
    for (int mt = 0; mt < 2; mt++) {
      bf8 Av = *(const bf8*)(pAf[mt] + k);
      bf8 Gv = *(const bf8*)(pAg[mt] + k);
#pragma unroll
      for (int nt = 0; nt < 4; nt++) {
        fa[mt][nt] = __builtin_amdgcn_mfma_f32_16x16x32_bf16(Av, Bv[nt], fa[mt][nt], 0, 0, 0);
        ga[mt][nt] = __builtin_amdgcn_mfma_f32_16x16x32_bf16(Gv, Bv[nt], ga[mt][nt], 0, 0, 0);
      }
    }
  }

  const float* bf_ = biasp + (size_t)layer * 128;
  const float* bg_ = biasp + 2048 + (size_t)layer * 128;
#pragma unroll
  for (int mt = 0; mt < 2; mt++) {
    int mb = w * 32 + mt * 16 + l4 * 4;
#pragma unroll
    for (int nt = 0; nt < 4; nt++) {
      s4 zp;
#pragma unroll
      for (int r = 0; r < 4; r++) {
        float f = fa[mt][nt][r] + bf_[mb + r];
        float g = ga[mt][nt][r] + bg_[mb + r];
        float th = 1.f - 2.f / (__expf(2.f * f) + 1.f);
        float sg = 1.f / (1.f + __expf(-g));
        zp[r] = f2bf(th * sg);
      }
      *(s4*)&zT[nt * 16 + l15][mb] = zp;
    }
  }
  __syncthreads();

  f32x4 acc[6][4];
#pragma unroll
  for (int i = 0; i < 6; i++)
#pragma unroll
    for (int j = 0; j < 4; j++) acc[i][j] = (f32x4)0.f;
  const short* pA[6];
#pragma unroll
  for (int mt = 0; mt < 6; mt++)
    pA[mt] = Ars + (size_t)(w * 96 + mt * 16 + l15) * 128 + l4 * 8;
#pragma unroll
  for (int kk = 0; kk < 4; kk++) {
    const int k = kk * 32;
    bf8 Bv[4];
#pragma unroll
    for (int nt = 0; nt < 4; nt++) Bv[nt] = *(const bf8*)&zT[nt * 16 + l15][k + l4 * 8];
#pragma unroll
    for (int mt = 0; mt < 6; mt++) {
      bf8 Av = *(const bf8*)(pA[mt] + k);
#pragma unroll
      for (int nt = 0; nt < 4; nt++)
        acc[mt][nt] = __builtin_amdgcn_mfma_f32_16x16x32_bf16(Av, Bv[nt], acc[mt][nt], 0, 0, 0);
    }
  }

  const float* br_ = biasp + 4096 + (size_t)layer * 128;
  const float* bs_ = biasp + 6144 + (size_t)layer * 256;
#pragma unroll
  for (int mt = 0; mt < 6; mt++) {
    int m = w * 96 + mt * 16 + l4 * 4;
#pragma unroll
    for (int nt = 0; nt < 4; nt++) {
      int t = t0 + nt * 16 + l15;
      if (m < 128) {
        s4 xv = *(const s4*)(xin + xbase + (size_t)t * CH + m);
        s4 ov;
#pragma unroll
        for (int r = 0; r < 4; r++)
          ov[r] = f2bf(bf2f(xv[r]) + acc[mt][nt][r] + br_[m + r]);
        *(s4*)(xout + xbase + (size_t)t * CH + m) = ov;
      } else if (m < 128 + SKIPC) {
        int c = m - 128;
        float* sp = skip + ((size_t)b * NQ + c) * TT + t;
#pragma unroll
        for (int r = 0; r < 4; r++) {
          float v = acc[mt][nt][r] + bs_[c + r];
          if (!first) v += sp[(size_t)r * TT];
          sp[(size_t)r * TT] = v;
        }
      }
    }
  }
}

__global__ __launch_bounds__(256) void k_head_mfma(
    const float* skip, const short* __restrict__ W1p, const float* __restrict__ b1,
    const short* __restrict__ W2p, const float* __restrict__ b2, float* out) {
  __shared__ short hT[NTF][264];
  __shared__ short h2T[NTF][264];
  const int b = blockIdx.y;
  const int t0 = blockIdx.x * NTF;
  const int tid = threadIdx.x;
  const int lane = tid & 63, w = tid >> 6;
  const int l15 = lane & 15, l4 = lane >> 4;

  for (int u = tid; u < 256 * 16; u += 256) {
    int c = u >> 4, tq = u & 15;
    if (c < SKIPC) {
      f32x4 v = *(const f32x4*)(skip + ((size_t)b * NQ + c) * TT + t0 + tq * 4);
#pragma unroll
      for (int j = 0; j < 4; j++) hT[tq * 4 + j][c] = f2bf(fmaxf(v[j], 0.f));
    } else {
#pragma unroll
      for (int j = 0; j < 4; j++) hT[tq * 4 + j][c] = 0;
    }
  }
  __syncthreads();

  f32x4 acc[4][4];
#pragma unroll
  for (int i = 0; i < 4; i++)
#pragma unroll
    for (int j = 0; j < 4; j++) acc[i][j] = (f32x4)0.f;
#pragma unroll
  for (int kk = 0; kk < 8; kk++) {
    const int k = kk * 32;
    bf8 Bv[4];
#pragma unroll
    for (int nt = 0; nt < 4; nt++) Bv[nt] = *(const bf8*)&hT[nt * 16 + l15][k + l4 * 8];
#pragma unroll
    for (int mt = 0; mt < 4; mt++) {
      bf8 Av = *(const bf8*)(W1p + (size_t)(w * 64 + mt * 16 + l15) * 256 + k + l4 * 8);
#pragma unroll
      for (int nt = 0; nt < 4; nt++)
        acc[mt][nt] = __builtin_amdgcn_mfma_f32_16x16x32_bf16(Av, Bv[nt], acc[mt][nt], 0, 0, 0);
    }
  }
#pragma unroll
  for (int mt = 0; mt < 4; mt++) {
    int mb = w * 64 + mt * 16 + l4 * 4;
#pragma unroll
    for (int nt = 0; nt < 4; nt++) {
      s4 hp;
#pragma unroll
      for (int r = 0; r < 4; r++) hp[r] = f2bf(fmaxf(acc[mt][nt][r] + b1[mb + r], 0.f));
      *(s4*)&h2T[nt * 16 + l15][mb] = hp;
    }
  }
  __syncthreads();

#pragma unroll
  for (int i = 0; i < 4; i++)
#pragma unroll
    for (int j = 0; j < 4; j++) acc[i][j] = (f32x4)0.f;
#pragma unroll
  for (int kk = 0; kk < 8; kk++) {
    const int k = kk * 32;
    bf8 Bv[4];
#pragma unroll
    for (int nt = 0; nt < 4; nt++) Bv[nt] = *(const bf8*)&h2T[nt * 16 + l15][k + l4 * 8];
#pragma unroll
    for (int mt = 0; mt < 4; mt++) {
      bf8 Av = *(const bf8*)(W2p + (size_t)(w * 64 + mt * 16 + l15) * 256 + k + l4 * 8);
#pragma unroll
      for (int nt = 0; nt < 4; nt++)
        acc[mt][nt] = __builtin_amdgcn_mfma_f32_16x16x32_bf16(Av, Bv[nt], acc[mt][nt], 0, 0, 0);
    }
  }
#pragma unroll
  for (int mt = 0; mt < 4; mt++) {
    int q = w * 64 + mt * 16 + l4 * 4;
#pragma unroll
    for (int nt = 0; nt < 4; nt++) {
      int t = t0 + nt * 16 + l15;
#pragma unroll
      for (int r = 0; r < 4; r++)
        out[((size_t)b * NQ + q + r) * TT + t] = acc[mt][nt][r] + b2[q + r];
    }
  }
}

extern "C" void kernel_launch(void* const* d_in, const int* in_sizes, int n_in,
                              void* d_out, int out_size, void* d_ws, size_t ws_size,
                              hipStream_t stream) {
  const float* wave  = (const float*)d_in[0];
  const float* W_in  = (const float*)d_in[1];
  const float* b_in  = (const float*)d_in[2];
  const float* Wf    = (const float*)d_in[3];
  const float* bf    = (const float*)d_in[4];
  const float* Wg    = (const float*)d_in[5];
  const float* bg    = (const float*)d_in[6];
  const float* Wres  = (const float*)d_in[7];
  const float* bres  = (const float*)d_in[8];
  const float* Wskip = (const float*)d_in[9];
  const float* bskip = (const float*)d_in[10];
  const float* W1    = (const float*)d_in[11];
  const float* b1    = (const float*)d_in[12];
  const float* W2    = (const float*)d_in[13];
  const float* b2    = (const float*)d_in[14];
  float* out = (float*)d_out;

  char* ws = (char*)d_ws;
  short* xA    = (short*)ws;                    // 33,554,432 B
  short* xB    = (short*)(ws + 33554432);       // 33,554,432 B
  short* Afg   = (short*)(ws + 67108864);       //  2,097,152 B
  short* Ars   = (short*)(ws + 69206016);       //  1,572,864 B
  short* W1p   = (short*)(ws + 70778880);       //    131,072 B
  short* W2p   = (short*)(ws + 70909952);       //    131,072 B
  float* biasp = (float*)(ws + 71041024);       //     40,960 B
  short* Wskp  = (short*)(ws + 71081984);       //  1,048,576 B
  float* bsum  = (float*)(ws + 72130560);       //      1,024 B
  short* zg    = (short*)(ws + 72131584);       // nbg * 67,108,864 B
  const size_t BASE = 72131584ull;
  const size_t ZPB  = (size_t)TT * KZ * 2;      // 67,108,864 B per batch

  int nbg = 0;
  if      (ws_size >= BASE + 8 * ZPB) nbg = 8;
  else if (ws_size >= BASE + 4 * ZPB) nbg = 4;
  else if (ws_size >= BASE + 2 * ZPB) nbg = 2;
  else if (ws_size >= BASE + 1 * ZPB) nbg = 1;
  const int do2 = (ws_size >= BASE) ? 1 : 0;

  k_pack<<<1024, 256, 0, stream>>>(Wf, Wg, Wres, Wskip, W1, W2, bf, bg, bres, bskip,
                                   Afg, Ars, W1p, W2p, biasp, Wskp, bsum,
                                   nbg > 0 ? 1 : 0);
  k_input<<<(NBATCH * TT) / 256, 256, 0, stream>>>(wave, W_in, b_in, xA);

  static const int dils[16] = {1, 2, 4, 8, 16, 32, 64, 128,
                               1, 2, 4, 8, 16, 32, 64, 128};
  if (nbg > 0) {
    for (int g = 0; g < NBATCH; g += nbg) {
      const short* xi = xA;
      short* xo = xB;
      for (int i = 0; i < 16; i++) {
        k_res2<<<dim3(TT / NT2, nbg), 512, 0, stream>>>(
            xi, xo, zg, Afg + (size_t)i * 65536, Ars + (size_t)i * 49152,
            biasp, i, dils[i], g);
        short* tmp = (short*)xi; xi = xo; xo = tmp;
      }
      k_head2<<<dim3(TT / NT2, nbg), 512, 0, stream>>>(zg, Wskp, bsum, W1p, b1,
                                                       W2p, b2, out, g);
    }
  } else {
    const short* xi = xA;
    short* xo = xB;
    for (int i = 0; i < 16; i++) {
      k_res_mfma<<<dim3(TT / NTF, NBATCH), 256, 0, stream>>>(
          xi, xo, out, Afg + (size_t)i * 65536, Ars + (size_t)i * 49152,
          biasp, i, dils[i], i == 0 ? 1 : 0);
      short* tmp = (short*)xi; xi = xo; xo = tmp;
    }
    k_head_mfma<<<dim3(TT / NTF, NBATCH), 256, 0, stream>>>(out, W1p, b1, W2p, b2, out);
  }
}

// Round 6
// 2499.884 us; speedup vs baseline: 1.4297x; 1.4297x over previous
//
#include <hip/hip_runtime.h>
#include <cstddef>

#define TT 16384
#define NBATCH 8
#define CH 128        // padded residual channels
#define RES 120
#define SKIPC 240
#define NQ 256
#define NT2 32        // timesteps per workgroup (fast path)
#define NTF 64        // timesteps per workgroup (fallback path)
#define KZ 2048       // 16 layers * 128 ch, head skip-GEMM K

typedef __attribute__((ext_vector_type(8))) short bf8;   // 8 bf16 (4 VGPR)
typedef __attribute__((ext_vector_type(4))) short s4;    // 4 bf16 (8B)
typedef __attribute__((ext_vector_type(4))) float f32x4;

__device__ __forceinline__ short f2bf(float f) {
  unsigned u = __builtin_bit_cast(unsigned, f);
  u += 0x7fffu + ((u >> 16) & 1u);
  return (short)(u >> 16);
}
__device__ __forceinline__ float bf2f(short s) {
  unsigned u = ((unsigned)(unsigned short)s) << 16;
  return __builtin_bit_cast(float, u);
}

// ---- pack all weights to bf16, padded, MFMA row-major [M][K] ----
__global__ void k_pack(const float* __restrict__ Wf, const float* __restrict__ Wg,
                       const float* __restrict__ Wres, const float* __restrict__ Wskip,
                       const float* __restrict__ W1, const float* __restrict__ W2,
                       const float* __restrict__ bf, const float* __restrict__ bg,
                       const float* __restrict__ bres, const float* __restrict__ bskip,
                       short* __restrict__ Afg, short* __restrict__ Ars,
                       short* __restrict__ W1p, short* __restrict__ W2p,
                       float* __restrict__ biasp,
                       short* __restrict__ Wskp, float* __restrict__ bsum, int do2) {
  const int NAFG = 16 * 256 * 256;   // 1048576
  const int NARS = 16 * 384 * 128;   // 786432
  const int NW = 256 * 256;          // 65536
  const int NBIA = 16 * (128 * 3 + 256);
  const int NWSK = 256 * 2048;
  const int total = NAFG + NARS + 2 * NW + NBIA + NWSK + 256;
  for (int idx = blockIdx.x * blockDim.x + threadIdx.x; idx < total;
       idx += gridDim.x * blockDim.x) {
    if (idx < NAFG) {
      int i = idx >> 16, rem = idx & 65535, m = rem >> 8, k = rem & 255;
      int tap = k >> 7, ci = k & 127;
      float v = 0.f;
      if (ci < 120) {
        if (m < 120) v = Wf[((i * 120 + m) * 120 + ci) * 2 + tap];
        else if (m >= 128 && m < 248) v = Wg[((i * 120 + (m - 128)) * 120 + ci) * 2 + tap];
      }
      Afg[idx] = f2bf(v);
    } else if (idx < NAFG + NARS) {
      int j = idx - NAFG;
      int i = j / 49152, rem = j % 49152, m = rem >> 7, k = rem & 127;
      float v = 0.f;
      if (k < 120) {
        if (m < 120) v = Wres[(i * 120 + m) * 120 + k];
        else if (m >= 128 && m < 368) v = Wskip[(i * 240 + (m - 128)) * 120 + k];
      }
      Ars[j] = f2bf(v);
    } else if (idx < NAFG + NARS + NW) {
      int j = idx - NAFG - NARS, q = j >> 8, k = j & 255;
      W1p[j] = f2bf(k < 240 ? W1[q * 240 + k] : 0.f);
    } else if (idx < NAFG + NARS + 2 * NW) {
      int j = idx - NAFG - NARS - NW;
      W2p[j] = f2bf(W2[j]);
    } else if (idx < NAFG + NARS + 2 * NW + NBIA) {
      int j = idx - NAFG - NARS - 2 * NW;
      float v = 0.f;
      if (j < 2048) { int i = j >> 7, c = j & 127; if (c < 120) v = bf[i * 120 + c]; }
      else if (j < 4096) { int jj = j - 2048; int i = jj >> 7, c = jj & 127; if (c < 120) v = bg[i * 120 + c]; }
      else if (j < 6144) { int jj = j - 4096; int i = jj >> 7, c = jj & 127; if (c < 120) v = bres[i * 120 + c]; }
      else { int jj = j - 6144; int i = jj >> 8, c = jj & 255; if (c < 240) v = bskip[i * 240 + c]; }
      biasp[j] = v;
    } else if (idx < NAFG + NARS + 2 * NW + NBIA + NWSK) {
      if (do2) {
        int j = idx - NAFG - NARS - 2 * NW - NBIA;
        int m = j >> 11, k = j & 2047;
        int layer = k >> 7, ci = k & 127;
        float v = 0.f;
        if (m < 240 && ci < 120) v = Wskip[((size_t)layer * 240 + m) * 120 + ci];
        Wskp[j] = f2bf(v);
      }
    } else {
      if (do2) {
        int m = idx - (NAFG + NARS + 2 * NW + NBIA + NWSK);
        float v = 0.f;
        if (m < 240)
          for (int l = 0; l < 16; l++) v += bskip[l * 240 + m];
        bsum[m] = v;
      }
    }
  }
}

// x0[b][t][c] = bf16(W_in[c]*wave[b][t] + b_in[c]), pad channels zero
__global__ void k_input(const float* __restrict__ wave, const float* __restrict__ win,
                        const float* __restrict__ bin, short* __restrict__ x0) {
  int idx = blockIdx.x * blockDim.x + threadIdx.x;  // one per (b,t)
  if (idx >= NBATCH * TT) return;
  float wv = wave[idx];
  short* row = x0 + (size_t)idx * CH;
  for (int c = 0; c < CH; c += 4) {
    s4 v;
#pragma unroll
    for (int j = 0; j < 4; j++)
      v[j] = (c + j < 120) ? f2bf(win[c + j] * wv + bin[c + j]) : (short)0;
    *(s4*)(row + c) = v;
  }
}

// ================== zg PATH: residual block (256 thr, NT2=32, LDS-staged B) ==================
__global__ __launch_bounds__(256) void k_res2(
    const short* __restrict__ xin, short* __restrict__ xout,
    short* __restrict__ zg,
    const short* __restrict__ Afg, const short* __restrict__ Ars,
    const float* __restrict__ biasp, int layer, int dil, int b_off) {
  __shared__ short xc[NT2][136];
  __shared__ short xd[NT2][136];
  __shared__ short zT[NT2][136];
  const int bl = blockIdx.y;          // group-local batch
  const int b = b_off + bl;           // global batch
  const int t0 = blockIdx.x * NT2;
  const int tid = threadIdx.x;
  const int lane = tid & 63, w = tid >> 6;   // w 0..3
  const int l15 = lane & 15, l4 = lane >> 4;
  const size_t xbase = (size_t)b * TT * CH;

  // stage current + delayed x tiles (coalesced 16B loads; zero-fill t<0)
#pragma unroll
  for (int j = 0; j < 2; j++) {
    int i = tid + j * 256;            // 512 items: 32 rows x 16 chunks
    int t = i >> 4, c8 = i & 15;
    *(bf8*)&xc[t][c8 * 8] = *(const bf8*)(xin + xbase + (size_t)(t0 + t) * CH + c8 * 8);
    int ts = t0 + t - dil;
    bf8 vd = (bf8)(short)0;
    if (ts >= 0) vd = *(const bf8*)(xin + xbase + (size_t)ts * CH + c8 * 8);
    *(bf8*)&xd[t][c8 * 8] = vd;
  }
  __syncthreads();

  // ---------- fg GEMM: M=256 (f rows w*32.., g rows 128+w*32..), K=256, N=32 ----------
  f32x4 fa[2][2], ga[2][2];
#pragma unroll
  for (int i = 0; i < 2; i++)
#pragma unroll
    for (int j = 0; j < 2; j++) { fa[i][j] = (f32x4)0.f; ga[i][j] = (f32x4)0.f; }
  const short* pAf[2];
  const short* pAg[2];
#pragma unroll
  for (int mt = 0; mt < 2; mt++) {
    pAf[mt] = Afg + (size_t)(w * 32 + mt * 16 + l15) * 256 + l4 * 8;
    pAg[mt] = Afg + (size_t)(128 + w * 32 + mt * 16 + l15) * 256 + l4 * 8;
  }
#pragma unroll
  for (int kk = 0; kk < 8; kk++) {
    const int k = kk * 32;  // k<128: delayed tap, k>=128: current tap
    bf8 Bv[2];
#pragma unroll
    for (int nt = 0; nt < 2; nt++)
      Bv[nt] = (kk < 4) ? *(const bf8*)&xd[nt * 16 + l15][k + l4 * 8]
                        : *(const bf8*)&xc[nt * 16 + l15][(k - 128) + l4 * 8];
#pragma unroll
    for (int mt = 0; mt < 2; mt++) {
      bf8 Av = *(const bf8*)(pAf[mt] + k);
      bf8 Gv = *(const bf8*)(pAg[mt] + k);
#pragma unroll
      for (int nt = 0; nt < 2; nt++) {
        fa[mt][nt] = __builtin_amdgcn_mfma_f32_16x16x32_bf16(Av, Bv[nt], fa[mt][nt], 0, 0, 0);
        ga[mt][nt] = __builtin_amdgcn_mfma_f32_16x16x32_bf16(Gv, Bv[nt], ga[mt][nt], 0, 0, 0);
      }
    }
  }

  // activation -> zT (transposed, [t][c])
  const float* bf_ = biasp + (size_t)layer * 128;
  const float* bg_ = biasp + 2048 + (size_t)layer * 128;
#pragma unroll
  for (int mt = 0; mt < 2; mt++) {
    const int mb = w * 32 + mt * 16 + l4 * 4;
#pragma unroll
    for (int nt = 0; nt < 2; nt++) {
      s4 zp;
#pragma unroll
      for (int r = 0; r < 4; r++) {
        float f = fa[mt][nt][r] + bf_[mb + r];
        float g = ga[mt][nt][r] + bg_[mb + r];
        float th = 1.f - 2.f / (__expf(2.f * f) + 1.f);
        float sg = 1.f / (1.f + __expf(-g));
        zp[r] = f2bf(th * sg);
      }
      *(s4*)&zT[nt * 16 + l15][mb] = zp;
    }
  }
  __syncthreads();

  // z write to global (nontemporal; consumed by head later)
#pragma unroll
  for (int j = 0; j < 2; j++) {
    int i = tid + j * 256;
    int t = i >> 4, c8 = i & 15;
    bf8 v = *(const bf8*)&zT[t][c8 * 8];
    __builtin_nontemporal_store(
        v, (bf8*)(zg + ((size_t)(bl * TT + t0 + t) * 16 + layer) * 128 + c8 * 8));
  }

  // ---------- res GEMM: M=128 (rows w*32), K=128, N=32 ----------
  f32x4 acc[2][2];
#pragma unroll
  for (int i = 0; i < 2; i++)
#pragma unroll
    for (int j = 0; j < 2; j++) acc[i][j] = (f32x4)0.f;
  const short* pA[2];
#pragma unroll
  for (int mt = 0; mt < 2; mt++)
    pA[mt] = Ars + (size_t)(w * 32 + mt * 16 + l15) * 128 + l4 * 8;
#pragma unroll
  for (int kk = 0; kk < 4; kk++) {
    const int k = kk * 32;
    bf8 Bv[2];
#pragma unroll
    for (int nt = 0; nt < 2; nt++) Bv[nt] = *(const bf8*)&zT[nt * 16 + l15][k + l4 * 8];
#pragma unroll
    for (int mt = 0; mt < 2; mt++) {
      bf8 Av = *(const bf8*)(pA[mt] + k);
#pragma unroll
      for (int nt = 0; nt < 2; nt++)
        acc[mt][nt] = __builtin_amdgcn_mfma_f32_16x16x32_bf16(Av, Bv[nt], acc[mt][nt], 0, 0, 0);
    }
  }

  const float* br_ = biasp + 4096 + (size_t)layer * 128;
#pragma unroll
  for (int mt = 0; mt < 2; mt++) {
    const int m = w * 32 + mt * 16 + l4 * 4;
#pragma unroll
    for (int nt = 0; nt < 2; nt++) {
      int t = t0 + nt * 16 + l15;
      s4 xv = *(const s4*)&xc[nt * 16 + l15][m];   // x from LDS (same tile)
      s4 ov;
#pragma unroll
      for (int r = 0; r < 4; r++)
        ov[r] = f2bf(bf2f(xv[r]) + acc[mt][nt][r] + br_[m + r]);
      *(s4*)(xout + xbase + (size_t)t * CH + m) = ov;
    }
  }
}

// ====== zg PATH head (256 thr, NT2=32): LDS-chunked skip GEMM K=2048 + W1 + W2 ======
__global__ __launch_bounds__(256) void k_head2(
    const short* __restrict__ zg, const short* __restrict__ Wskp,
    const float* __restrict__ bsum,
    const short* __restrict__ W1p, const float* __restrict__ b1,
    const short* __restrict__ W2p, const float* __restrict__ b2,
    float* __restrict__ out, int b_off) {
  __shared__ short bufA[NT2][264];
  __shared__ short bufB[NT2][264];
  const int bl = blockIdx.y;
  const int b = b_off + bl;
  const int t0 = blockIdx.x * NT2;
  const int tid = threadIdx.x;
  const int lane = tid & 63, w = tid >> 6;   // w 0..3
  const int l15 = lane & 15, l4 = lane >> 4;

  f32x4 acc[4][2];
#pragma unroll
  for (int i = 0; i < 4; i++)
#pragma unroll
    for (int j = 0; j < 2; j++) acc[i][j] = (f32x4)0.f;

  const short* zrow = zg + (size_t)(bl * TT + t0) * KZ;

  // skip GEMM: M=256 (wave rows w*64 + mt*16), K=2048 in 8 chunks of 256, N=32
  // double-buffered LDS B; chunk c+1 global loads issued before compute of c
#pragma unroll
  for (int j = 0; j < 4; j++) {
    int i = tid + j * 256;              // 1024 items: 32 rows x 32 chunks of 8 shorts
    int t = i >> 5, c8 = i & 31;
    *(bf8*)&bufA[t][c8 * 8] = *(const bf8*)(zrow + (size_t)t * KZ + c8 * 8);
  }
  __syncthreads();
  for (int c = 0; c < 8; c++) {
    short (*cur)[264] = (c & 1) ? bufB : bufA;
    short (*nxt)[264] = (c & 1) ? bufA : bufB;
    if (c < 7) {
#pragma unroll
      for (int j = 0; j < 4; j++) {
        int i = tid + j * 256;
        int t = i >> 5, c8 = i & 31;
        *(bf8*)&nxt[t][c8 * 8] =
            *(const bf8*)(zrow + (size_t)t * KZ + (c + 1) * 256 + c8 * 8);
      }
    }
#pragma unroll
    for (int kk = 0; kk < 8; kk++) {
      const int k = kk * 32;
      bf8 Bv[2];
#pragma unroll
      for (int nt = 0; nt < 2; nt++)
        Bv[nt] = *(const bf8*)&cur[nt * 16 + l15][k + l4 * 8];
#pragma unroll
      for (int mt = 0; mt < 4; mt++) {
        bf8 Av = *(const bf8*)(Wskp + (size_t)(w * 64 + mt * 16 + l15) * KZ +
                               c * 256 + k + l4 * 8);
#pragma unroll
        for (int nt = 0; nt < 2; nt++)
          acc[mt][nt] = __builtin_amdgcn_mfma_f32_16x16x32_bf16(Av, Bv[nt], acc[mt][nt], 0, 0, 0);
      }
    }
    __syncthreads();
  }

  // h = relu(skip + bsum) -> bufA ([t][c], K pad 240->256 rows are zero from Wskp pad)
#pragma unroll
  for (int mt = 0; mt < 4; mt++) {
    const int mb = w * 64 + mt * 16 + l4 * 4;
#pragma unroll
    for (int nt = 0; nt < 2; nt++) {
      s4 hp;
#pragma unroll
      for (int r = 0; r < 4; r++)
        hp[r] = f2bf(fmaxf(acc[mt][nt][r] + bsum[mb + r], 0.f));
      *(s4*)&bufA[nt * 16 + l15][mb] = hp;
    }
  }
  __syncthreads();

  // GEMM1: W1p, M=256 K=256 N=32 -> relu -> bufB
#pragma unroll
  for (int i = 0; i < 4; i++)
#pragma unroll
    for (int j = 0; j < 2; j++) acc[i][j] = (f32x4)0.f;
#pragma unroll
  for (int kk = 0; kk < 8; kk++) {
    const int k = kk * 32;
    bf8 Bv[2];
#pragma unroll
    for (int nt = 0; nt < 2; nt++) Bv[nt] = *(const bf8*)&bufA[nt * 16 + l15][k + l4 * 8];
#pragma unroll
    for (int mt = 0; mt < 4; mt++) {
      bf8 Av = *(const bf8*)(W1p + (size_t)(w * 64 + mt * 16 + l15) * 256 + k + l4 * 8);
#pragma unroll
      for (int nt = 0; nt < 2; nt++)
        acc[mt][nt] = __builtin_amdgcn_mfma_f32_16x16x32_bf16(Av, Bv[nt], acc[mt][nt], 0, 0, 0);
    }
  }
#pragma unroll
  for (int mt = 0; mt < 4; mt++) {
    const int mb = w * 64 + mt * 16 + l4 * 4;
#pragma unroll
    for (int nt = 0; nt < 2; nt++) {
      s4 hp;
#pragma unroll
      for (int r = 0; r < 4; r++)
        hp[r] = f2bf(fmaxf(acc[mt][nt][r] + b1[mb + r], 0.f));
      *(s4*)&bufB[nt * 16 + l15][mb] = hp;
    }
  }
  __syncthreads();

  // GEMM2: W2p, M=256 K=256 N=32 -> out
#pragma unroll
  for (int i = 0; i < 4; i++)
#pragma unroll
    for (int j = 0; j < 2; j++) acc[i][j] = (f32x4)0.f;
#pragma unroll
  for (int kk = 0; kk < 8; kk++) {
    const int k = kk * 32;
    bf8 Bv[2];
#pragma unroll
    for (int nt = 0; nt < 2; nt++) Bv[nt] = *(const bf8*)&bufB[nt * 16 + l15][k + l4 * 8];
#pragma unroll
    for (int mt = 0; mt < 4; mt++) {
      bf8 Av = *(const bf8*)(W2p + (size_t)(w * 64 + mt * 16 + l15) * 256 + k + l4 * 8);
#pragma unroll
      for (int nt = 0; nt < 2; nt++)
        acc[mt][nt] = __builtin_amdgcn_mfma_f32_16x16x32_bf16(Av, Bv[nt], acc[mt][nt], 0, 0, 0);
    }
  }
#pragma unroll
  for (int mt = 0; mt < 4; mt++) {
    const int q = w * 64 + mt * 16 + l4 * 4;
#pragma unroll
    for (int nt = 0; nt < 2; nt++) {
      int t = t0 + nt * 16 + l15;
#pragma unroll
      for (int r = 0; r < 4; r++) {
        float v = acc[mt][nt][r] + b2[q + r];
        __builtin_nontemporal_store(v, out + ((size_t)b * NQ + q + r) * TT + t);
      }
    }
  }
}

// ================== FALLBACK PATH (round-2, passing; NTF=64, 256 thr) ==================
__global__ __launch_bounds__(256) void k_res_mfma(
    const short* __restrict__ xin, short* __restrict__ xout,
    float* __restrict__ skip,
    const short* __restrict__ Afg, const short* __restrict__ Ars,
    const float* __restrict__ biasp, int layer, int dil, int first) {
  __shared__ short zT[NTF][136];
  const int b = blockIdx.y;
  const int t0 = blockIdx.x * NTF;
  const int tid = threadIdx.x;
  const int lane = tid & 63, w = tid >> 6;
  const int l15 = lane & 15, l4 = lane >> 4;
  const size_t xbase = (size_t)b * TT * CH;

  f32x4 fa[2][4], ga[2][4];
#pragma unroll
  for (int i = 0; i < 2; i++)
#pragma unroll
    for (int j = 0; j < 4; j++) { fa[i][j] = (f32x4)0.f; ga[i][j] = (f32x4)0.f; }

  const short* pBd[4];
  const short* pBc[4];
  bool vld[4];
#pragma unroll
  for (int nt = 0; nt < 4; nt++) {
    int t = t0 + nt * 16 + l15;
    int ts = t - dil;
    vld[nt] = (ts >= 0);
    pBd[nt] = xin + xbase + (size_t)(vld[nt] ? ts : 0) * CH + l4 * 8;
    pBc[nt] = xin + xbase + (size_t)t * CH + l4 * 8;
  }
  const short* pAf[2];
  const short* pAg[2];
#pragma unroll
  for (int mt = 0; mt < 2; mt++) {
    pAf[mt] = Afg + (size_t)(w * 32 + mt * 16 + l15) * 256 + l4 * 8;
    pAg[mt] = Afg + (size_t)(128 + w * 32 + mt * 16 + l15) * 256 + l4 * 8;
  }
  const bf8 zv = (bf8)(short)0;
#pragma unroll
  for (int kk = 0; kk < 8; kk++) {
    const int k = kk * 32;
    bf8 Bv[4];
#pragma unroll
    for (int nt = 0; nt < 4; nt++) {
      if (kk < 4) {
        bf8 v = *(const bf8*)(pBd[nt] + k);
        Bv[nt] = vld[nt] ? v : zv;
      } else {
        Bv[nt] = *(const bf8*)(pBc[nt] + (k - 128));
      }
    }
#pragma unroll
    for (int mt = 0; mt < 2; mt++) {
      bf8 Av = *(const bf8*)(pAf[mt] + k);
      bf8 Gv = *(const bf8*)(pAg[mt] + k);
#pragma unroll
      for (int nt = 0; nt < 4; nt++) {
        fa[mt][nt] = __builtin_amdgcn_mfma_f32_16x16x32_bf16(Av, Bv[nt], fa[mt][nt], 0, 0, 0);
        ga[mt][nt] = __builtin_amdgcn_mfma_f32_16x16x32_bf16(Gv, Bv[nt], ga[mt][nt], 0, 0, 0);
      }
    }
  }

  const float* bf_ = biasp + (size_t)layer * 128;
  const float* bg_ = biasp + 2048 + (size_t)layer * 128;
#pragma unroll
  for (int mt = 0; mt < 2; mt++) {
    int mb = w * 32 + mt * 16 + l4 * 4;
#pragma unroll
    for (int nt = 0; nt < 4; nt++) {
      s4 zp;
#pragma unroll
      for (int r = 0; r < 4; r++) {
        float f = fa[mt][nt][r] + bf_[mb + r];
        float g = ga[mt][nt][r] + bg_[mb + r];
        float th = 1.f - 2.f / (__expf(2.f * f) + 1.f);
        float sg = 1.f / (1.f + __expf(-g));
        zp[r] = f2bf(th * sg);
      }
      *(s4*)&zT[nt * 16 + l15][mb] = zp;
    }
  }
  __syncthreads();

  f32x4 acc[6][4];
#pragma unroll
  for (int i = 0; i < 6; i++)
#pragma unroll
    for (int j = 0; j < 4; j++) acc[i][j] = (f32x4)0.f;
  const short* pA[6];
#pragma unroll
  for (int mt = 0; mt < 6; mt++)
    pA[mt] = Ars + (size_t)(w * 96 + mt * 16 + l15) * 128 + l4 * 8;
#pragma unroll
  for (int kk = 0; kk < 4; kk++) {
    const int k = kk * 32;
    bf8 Bv[4];
#pragma unroll
    for (int nt = 0; nt < 4; nt++) Bv[nt] = *(const bf8*)&zT[nt * 16 + l15][k + l4 * 8];
#pragma unroll
    for (int mt = 0; mt < 6; mt++) {
      bf8 Av = *(const bf8*)(pA[mt] + k);
#pragma unroll
      for (int nt = 0; nt < 4; nt++)
        acc[mt][nt] = __builtin_amdgcn_mfma_f32_16x16x32_bf16(Av, Bv[nt], acc[mt][nt], 0, 0, 0);
    }
  }

  const float* br_ = biasp + 4096 + (size_t)layer * 128;
  const float* bs_ = biasp + 6144 + (size_t)layer * 256;
#pragma unroll
  for (int mt = 0; mt < 6; mt++) {
    int m = w * 96 + mt * 16 + l4 * 4;
#pragma unroll
    for (int nt = 0; nt < 4; nt++) {
      int t = t0 + nt * 16 + l15;
      if (m < 128) {
        s4 xv = *(const s4*)(xin + xbase + (size_t)t * CH + m);
        s4 ov;
#pragma unroll
        for (int r = 0; r < 4; r++)
          ov[r] = f2bf(bf2f(xv[r]) + acc[mt][nt][r] + br_[m + r]);
        *(s4*)(xout + xbase + (size_t)t * CH + m) = ov;
      } else if (m < 128 + SKIPC) {
        int c = m - 128;
        float* sp = skip + ((size_t)b * NQ + c) * TT + t;
#pragma unroll
        for (int r = 0; r < 4; r++) {
          float v = acc[mt][nt][r] + bs_[c + r];
          if (!first) v += sp[(size_t)r * TT];
          sp[(size_t)r * TT] = v;
        }
      }
    }
  }
}

__global__ __launch_bounds__(256) void k_head_mfma(
    const float* skip, const short* __restrict__ W1p, const float* __restrict__ b1,
    const short* __restrict__ W2p, const float* __restrict__ b2, float* out) {
  __shared__ short hT[NTF][264];
  __shared__ short h2T[NTF][264];
  const int b = blockIdx.y;
  const int t0 = blockIdx.x * NTF;
  const int tid = threadIdx.x;
  const int lane = tid & 63, w = tid >> 6;
  const int l15 = lane & 15, l4 = lane >> 4;

  for (int u = tid; u < 256 * 16; u += 256) {
    int c = u >> 4, tq = u & 15;
    if (c < SKIPC) {
      f32x4 v = *(const f32x4*)(skip + ((size_t)b * NQ + c) * TT + t0 + tq * 4);
#pragma unroll
      for (int j = 0; j < 4; j++) hT[tq * 4 + j][c] = f2bf(fmaxf(v[j], 0.f));
    } else {
#pragma unroll
      for (int j = 0; j < 4; j++) hT[tq * 4 + j][c] = 0;
    }
  }
  __syncthreads();

  f32x4 acc[4][4];
#pragma unroll
  for (int i = 0; i < 4; i++)
#pragma unroll
    for (int j = 0; j < 4; j++) acc[i][j] = (f32x4)0.f;
#pragma unroll
  for (int kk = 0; kk < 8; kk++) {
    const int k = kk * 32;
    bf8 Bv[4];
#pragma unroll
    for (int nt = 0; nt < 4; nt++) Bv[nt] = *(const bf8*)&hT[nt * 16 + l15][k + l4 * 8];
#pragma unroll
    for (int mt = 0; mt < 4; mt++) {
      bf8 Av = *(const bf8*)(W1p + (size_t)(w * 64 + mt * 16 + l15) * 256 + k + l4 * 8);
#pragma unroll
      for (int nt = 0; nt < 4; nt++)
        acc[mt][nt] = __builtin_amdgcn_mfma_f32_16x16x32_bf16(Av, Bv[nt], acc[mt][nt], 0, 0, 0);
    }
  }
#pragma unroll
  for (int mt = 0; mt < 4; mt++) {
    int mb = w * 64 + mt * 16 + l4 * 4;
#pragma unroll
    for (int nt = 0; nt < 4; nt++) {
      s4 hp;
#pragma unroll
      for (int r = 0; r < 4; r++) hp[r] = f2bf(fmaxf(acc[mt][nt][r] + b1[mb + r], 0.f));
      *(s4*)&h2T[nt * 16 + l15][mb] = hp;
    }
  }
  __syncthreads();

#pragma unroll
  for (int i = 0; i < 4; i++)
#pragma unroll
    for (int j = 0; j < 4; j++) acc[i][j] = (f32x4)0.f;
#pragma unroll
  for (int kk = 0; kk < 8; kk++) {
    const int k = kk * 32;
    bf8 Bv[4];
#pragma unroll
    for (int nt = 0; nt < 4; nt++) Bv[nt] = *(const bf8*)&h2T[nt * 16 + l15][k + l4 * 8];
#pragma unroll
    for (int mt = 0; mt < 4; mt++) {
      bf8 Av = *(const bf8*)(W2p + (size_t)(w * 64 + mt * 16 + l15) * 256 + k + l4 * 8);
#pragma unroll
      for (int nt = 0; nt < 4; nt++)
        acc[mt][nt] = __builtin_amdgcn_mfma_f32_16x16x32_bf16(Av, Bv[nt], acc[mt][nt], 0, 0, 0);
    }
  }
#pragma unroll
  for (int mt = 0; mt < 4; mt++) {
    int q = w * 64 + mt * 16 + l4 * 4;
#pragma unroll
    for (int nt = 0; nt < 4; nt++) {
      int t = t0 + nt * 16 + l15;
#pragma unroll
      for (int r = 0; r < 4; r++)
        out[((size_t)b * NQ + q + r) * TT + t] = acc[mt][nt][r] + b2[q + r];
    }
  }
}

extern "C" void kernel_launch(void* const* d_in, const int* in_sizes, int n_in,
                              void* d_out, int out_size, void* d_ws, size_t ws_size,
                              hipStream_t stream) {
  const float* wave  = (const float*)d_in[0];
  const float* W_in  = (const float*)d_in[1];
  const float* b_in  = (const float*)d_in[2];
  const float* Wf    = (const float*)d_in[3];
  const float* bf    = (const float*)d_in[4];
  const float* Wg    = (const float*)d_in[5];
  const float* bg    = (const float*)d_in[6];
  const float* Wres  = (const float*)d_in[7];
  const float* bres  = (const float*)d_in[8];
  const float* Wskip = (const float*)d_in[9];
  const float* bskip = (const float*)d_in[10];
  const float* W1    = (const float*)d_in[11];
  const float* b1    = (const float*)d_in[12];
  const float* W2    = (const float*)d_in[13];
  const float* b2    = (const float*)d_in[14];
  float* out = (float*)d_out;

  char* ws = (char*)d_ws;
  short* xA    = (short*)ws;                    // 33,554,432 B
  short* xB    = (short*)(ws + 33554432);       // 33,554,432 B
  short* Afg   = (short*)(ws + 67108864);       //  2,097,152 B
  short* Ars   = (short*)(ws + 69206016);       //  1,572,864 B
  short* W1p   = (short*)(ws + 70778880);       //    131,072 B
  short* W2p   = (short*)(ws + 70909952);       //    131,072 B
  float* biasp = (float*)(ws + 71041024);       //     40,960 B
  short* Wskp  = (short*)(ws + 71081984);       //  1,048,576 B
  float* bsum  = (float*)(ws + 72130560);       //      1,024 B
  short* zg    = (short*)(ws + 72131584);       // nbg * 67,108,864 B
  const size_t BASE = 72131584ull;
  const size_t ZPB  = (size_t)TT * KZ * 2;      // 67,108,864 B per batch

  int nbg = 0;
  if      (ws_size >= BASE + 8 * ZPB) nbg = 8;
  else if (ws_size >= BASE + 4 * ZPB) nbg = 4;
  else if (ws_size >= BASE + 2 * ZPB) nbg = 2;
  else if (ws_size >= BASE + 1 * ZPB) nbg = 1;

  k_pack<<<1024, 256, 0, stream>>>(Wf, Wg, Wres, Wskip, W1, W2, bf, bg, bres, bskip,
                                   Afg, Ars, W1p, W2p, biasp, Wskp, bsum,
                                   nbg > 0 ? 1 : 0);
  k_input<<<(NBATCH * TT) / 256, 256, 0, stream>>>(wave, W_in, b_in, xA);

  static const int dils[16] = {1, 2, 4, 8, 16, 32, 64, 128,
                               1, 2, 4, 8, 16, 32, 64, 128};
  if (nbg > 0) {
    for (int g = 0; g < NBATCH; g += nbg) {
      const short* xi = xA;
      short* xo = xB;
      for (int i = 0; i < 16; i++) {
        k_res2<<<dim3(TT / NT2, nbg), 256, 0, stream>>>(
            xi, xo, zg, Afg + (size_t)i * 65536, Ars + (size_t)i * 49152,
            biasp, i, dils[i], g);
        short* tmp = (short*)xi; xi = xo; xo = tmp;
      }
      k_head2<<<dim3(TT / NT2, nbg), 256, 0, stream>>>(zg, Wskp, bsum, W1p, b1,
                                                       W2p, b2, out, g);
    }
  } else {
    const short* xi = xA;
    short* xo = xB;
    for (int i = 0; i < 16; i++) {
      k_res_mfma<<<dim3(TT / NTF, NBATCH), 256, 0, stream>>>(
          xi, xo, out, Afg + (size_t)i * 65536, Ars + (size_t)i * 49152,
          biasp, i, dils[i], i == 0 ? 1 : 0);
      short* tmp = (short*)xi; xi = xo; xo = tmp;
    }
    k_head_mfma<<<dim3(TT / NTF, NBATCH), 256, 0, stream>>>(out, W1p, b1, W2p, b2, out);
  }
}

// Round 7
// 2138.545 us; speedup vs baseline: 1.6713x; 1.1690x over previous
//
#include <hip/hip_runtime.h>
#include <cstddef>

#define TT 16384
#define NBATCH 8
#define CH 128        // padded residual channels
#define RES 120
#define SKIPC 240
#define NQ 256
#define NT2 32        // timesteps per workgroup (res path)
#define NTF 64        // timesteps per workgroup (fallback path)
#define KZ 2048       // 16 layers * 128 ch, head skip-GEMM K

typedef __attribute__((ext_vector_type(8))) short bf8;   // 8 bf16 (4 VGPR)
typedef __attribute__((ext_vector_type(4))) short s4;    // 4 bf16 (8B)
typedef __attribute__((ext_vector_type(4))) float f32x4;

__device__ __forceinline__ short f2bf(float f) {
  unsigned u = __builtin_bit_cast(unsigned, f);
  u += 0x7fffu + ((u >> 16) & 1u);
  return (short)(u >> 16);
}
__device__ __forceinline__ float bf2f(short s) {
  unsigned u = ((unsigned)(unsigned short)s) << 16;
  return __builtin_bit_cast(float, u);
}

// ---- pack all weights to bf16, padded, MFMA row-major [M][K] ----
__global__ void k_pack(const float* __restrict__ Wf, const float* __restrict__ Wg,
                       const float* __restrict__ Wres, const float* __restrict__ Wskip,
                       const float* __restrict__ W1, const float* __restrict__ W2,
                       const float* __restrict__ bf, const float* __restrict__ bg,
                       const float* __restrict__ bres, const float* __restrict__ bskip,
                       short* __restrict__ Afg, short* __restrict__ Ars,
                       short* __restrict__ W1p, short* __restrict__ W2p,
                       float* __restrict__ biasp,
                       short* __restrict__ Wskp, float* __restrict__ bsum, int do2) {
  const int NAFG = 16 * 256 * 256;   // 1048576
  const int NARS = 16 * 384 * 128;   // 786432
  const int NW = 256 * 256;          // 65536
  const int NBIA = 16 * (128 * 3 + 256);
  const int NWSK = 256 * 2048;
  const int total = NAFG + NARS + 2 * NW + NBIA + NWSK + 256;
  for (int idx = blockIdx.x * blockDim.x + threadIdx.x; idx < total;
       idx += gridDim.x * blockDim.x) {
    if (idx < NAFG) {
      int i = idx >> 16, rem = idx & 65535, m = rem >> 8, k = rem & 255;
      int tap = k >> 7, ci = k & 127;
      float v = 0.f;
      if (ci < 120) {
        if (m < 120) v = Wf[((i * 120 + m) * 120 + ci) * 2 + tap];
        else if (m >= 128 && m < 248) v = Wg[((i * 120 + (m - 128)) * 120 + ci) * 2 + tap];
      }
      Afg[idx] = f2bf(v);
    } else if (idx < NAFG + NARS) {
      int j = idx - NAFG;
      int i = j / 49152, rem = j % 49152, m = rem >> 7, k = rem & 127;
      float v = 0.f;
      if (k < 120) {
        if (m < 120) v = Wres[(i * 120 + m) * 120 + k];
        else if (m >= 128 && m < 368) v = Wskip[(i * 240 + (m - 128)) * 120 + k];
      }
      Ars[j] = f2bf(v);
    } else if (idx < NAFG + NARS + NW) {
      int j = idx - NAFG - NARS, q = j >> 8, k = j & 255;
      W1p[j] = f2bf(k < 240 ? W1[q * 240 + k] : 0.f);
    } else if (idx < NAFG + NARS + 2 * NW) {
      int j = idx - NAFG - NARS - NW;
      W2p[j] = f2bf(W2[j]);
    } else if (idx < NAFG + NARS + 2 * NW + NBIA) {
      int j = idx - NAFG - NARS - 2 * NW;
      float v = 0.f;
      if (j < 2048) { int i = j >> 7, c = j & 127; if (c < 120) v = bf[i * 120 + c]; }
      else if (j < 4096) { int jj = j - 2048; int i = jj >> 7, c = jj & 127; if (c < 120) v = bg[i * 120 + c]; }
      else if (j < 6144) { int jj = j - 4096; int i = jj >> 7, c = jj & 127; if (c < 120) v = bres[i * 120 + c]; }
      else { int jj = j - 6144; int i = jj >> 8, c = jj & 255; if (c < 240) v = bskip[i * 240 + c]; }
      biasp[j] = v;
    } else if (idx < NAFG + NARS + 2 * NW + NBIA + NWSK) {
      if (do2) {
        int j = idx - NAFG - NARS - 2 * NW - NBIA;
        int m = j >> 11, k = j & 2047;
        int layer = k >> 7, ci = k & 127;
        float v = 0.f;
        if (m < 240 && ci < 120) v = Wskip[((size_t)layer * 240 + m) * 120 + ci];
        Wskp[j] = f2bf(v);
      }
    } else {
      if (do2) {
        int m = idx - (NAFG + NARS + 2 * NW + NBIA + NWSK);
        float v = 0.f;
        if (m < 240)
          for (int l = 0; l < 16; l++) v += bskip[l * 240 + m];
        bsum[m] = v;
      }
    }
  }
}

// x0[b][t][c] = bf16(W_in[c]*wave[b][t] + b_in[c]), pad channels zero
__global__ void k_input(const float* __restrict__ wave, const float* __restrict__ win,
                        const float* __restrict__ bin, short* __restrict__ x0) {
  int idx = blockIdx.x * blockDim.x + threadIdx.x;  // one per (b,t)
  if (idx >= NBATCH * TT) return;
  float wv = wave[idx];
  short* row = x0 + (size_t)idx * CH;
  for (int c = 0; c < CH; c += 4) {
    s4 v;
#pragma unroll
    for (int j = 0; j < 4; j++)
      v[j] = (c + j < 120) ? f2bf(win[c + j] * wv + bin[c + j]) : (short)0;
    *(s4*)(row + c) = v;
  }
}

// ================== zg PATH: residual block (256 thr, NT2=32, LDS-staged B) ==================
__global__ __launch_bounds__(256) void k_res2(
    const short* __restrict__ xin, short* __restrict__ xout,
    short* __restrict__ zg,
    const short* __restrict__ Afg, const short* __restrict__ Ars,
    const float* __restrict__ biasp, int layer, int dil, int b_off) {
  __shared__ short xc[NT2][136];
  __shared__ short xd[NT2][136];
  __shared__ short zT[NT2][136];
  const int bl = blockIdx.y;          // group-local batch
  const int b = b_off + bl;           // global batch
  const int t0 = blockIdx.x * NT2;
  const int tid = threadIdx.x;
  const int lane = tid & 63, w = tid >> 6;   // w 0..3
  const int l15 = lane & 15, l4 = lane >> 4;
  const size_t xbase = (size_t)b * TT * CH;

  // stage current + delayed x tiles (coalesced 16B loads; zero-fill t<0)
#pragma unroll
  for (int j = 0; j < 2; j++) {
    int i = tid + j * 256;            // 512 items: 32 rows x 16 chunks
    int t = i >> 4, c8 = i & 15;
    *(bf8*)&xc[t][c8 * 8] = *(const bf8*)(xin + xbase + (size_t)(t0 + t) * CH + c8 * 8);
    int ts = t0 + t - dil;
    bf8 vd = (bf8)(short)0;
    if (ts >= 0) vd = *(const bf8*)(xin + xbase + (size_t)ts * CH + c8 * 8);
    *(bf8*)&xd[t][c8 * 8] = vd;
  }
  __syncthreads();

  // ---------- fg GEMM: M=256 (f rows w*32.., g rows 128+w*32..), K=256, N=32 ----------
  f32x4 fa[2][2], ga[2][2];
#pragma unroll
  for (int i = 0; i < 2; i++)
#pragma unroll
    for (int j = 0; j < 2; j++) { fa[i][j] = (f32x4)0.f; ga[i][j] = (f32x4)0.f; }
  const short* pAf[2];
  const short* pAg[2];
#pragma unroll
  for (int mt = 0; mt < 2; mt++) {
    pAf[mt] = Afg + (size_t)(w * 32 + mt * 16 + l15) * 256 + l4 * 8;
    pAg[mt] = Afg + (size_t)(128 + w * 32 + mt * 16 + l15) * 256 + l4 * 8;
  }
#pragma unroll
  for (int kk = 0; kk < 8; kk++) {
    const int k = kk * 32;  // k<128: delayed tap, k>=128: current tap
    bf8 Bv[2];
#pragma unroll
    for (int nt = 0; nt < 2; nt++)
      Bv[nt] = (kk < 4) ? *(const bf8*)&xd[nt * 16 + l15][k + l4 * 8]
                        : *(const bf8*)&xc[nt * 16 + l15][(k - 128) + l4 * 8];
#pragma unroll
    for (int mt = 0; mt < 2; mt++) {
      bf8 Av = *(const bf8*)(pAf[mt] + k);
      bf8 Gv = *(const bf8*)(pAg[mt] + k);
#pragma unroll
      for (int nt = 0; nt < 2; nt++) {
        fa[mt][nt] = __builtin_amdgcn_mfma_f32_16x16x32_bf16(Av, Bv[nt], fa[mt][nt], 0, 0, 0);
        ga[mt][nt] = __builtin_amdgcn_mfma_f32_16x16x32_bf16(Gv, Bv[nt], ga[mt][nt], 0, 0, 0);
      }
    }
  }

  // activation -> zT (transposed, [t][c])
  const float* bf_ = biasp + (size_t)layer * 128;
  const float* bg_ = biasp + 2048 + (size_t)layer * 128;
#pragma unroll
  for (int mt = 0; mt < 2; mt++) {
    const int mb = w * 32 + mt * 16 + l4 * 4;
#pragma unroll
    for (int nt = 0; nt < 2; nt++) {
      s4 zp;
#pragma unroll
      for (int r = 0; r < 4; r++) {
        float f = fa[mt][nt][r] + bf_[mb + r];
        float g = ga[mt][nt][r] + bg_[mb + r];
        float th = 1.f - 2.f / (__expf(2.f * f) + 1.f);
        float sg = 1.f / (1.f + __expf(-g));
        zp[r] = f2bf(th * sg);
      }
      *(s4*)&zT[nt * 16 + l15][mb] = zp;
    }
  }
  __syncthreads();

  // z write to global (nontemporal; consumed by head later)
#pragma unroll
  for (int j = 0; j < 2; j++) {
    int i = tid + j * 256;
    int t = i >> 4, c8 = i & 15;
    bf8 v = *(const bf8*)&zT[t][c8 * 8];
    __builtin_nontemporal_store(
        v, (bf8*)(zg + ((size_t)(bl * TT + t0 + t) * 16 + layer) * 128 + c8 * 8));
  }

  // ---------- res GEMM: M=128 (rows w*32), K=128, N=32 ----------
  f32x4 acc[2][2];
#pragma unroll
  for (int i = 0; i < 2; i++)
#pragma unroll
    for (int j = 0; j < 2; j++) acc[i][j] = (f32x4)0.f;
  const short* pA[2];
#pragma unroll
  for (int mt = 0; mt < 2; mt++)
    pA[mt] = Ars + (size_t)(w * 32 + mt * 16 + l15) * 128 + l4 * 8;
#pragma unroll
  for (int kk = 0; kk < 4; kk++) {
    const int k = kk * 32;
    bf8 Bv[2];
#pragma unroll
    for (int nt = 0; nt < 2; nt++) Bv[nt] = *(const bf8*)&zT[nt * 16 + l15][k + l4 * 8];
#pragma unroll
    for (int mt = 0; mt < 2; mt++) {
      bf8 Av = *(const bf8*)(pA[mt] + k);
#pragma unroll
      for (int nt = 0; nt < 2; nt++)
        acc[mt][nt] = __builtin_amdgcn_mfma_f32_16x16x32_bf16(Av, Bv[nt], acc[mt][nt], 0, 0, 0);
    }
  }

  const float* br_ = biasp + 4096 + (size_t)layer * 128;
#pragma unroll
  for (int mt = 0; mt < 2; mt++) {
    const int m = w * 32 + mt * 16 + l4 * 4;
#pragma unroll
    for (int nt = 0; nt < 2; nt++) {
      int t = t0 + nt * 16 + l15;
      s4 xv = *(const s4*)&xc[nt * 16 + l15][m];   // x from LDS (same tile)
      s4 ov;
#pragma unroll
      for (int r = 0; r < 4; r++)
        ov[r] = f2bf(bf2f(xv[r]) + acc[mt][nt][r] + br_[m + r]);
      *(s4*)(xout + xbase + (size_t)t * CH + m) = ov;
    }
  }
}

// ====== k_skip: C[256 x rem*T] = Wskp[256x2048] . zg^T, h=relu(C+bsum) -> out overlay f32 ======
// grid: x = rem*(TT/128) N-tiles, y = 2 M-tiles; 256 thr, 4 waves (2x2), 64x64 C per wave
__global__ __launch_bounds__(256) void k_skip(
    const short* __restrict__ zg, const short* __restrict__ Wskp,
    const float* __restrict__ bsum, float* __restrict__ out, int b_off) {
  __shared__ short At[2][128][40];
  __shared__ short Bt[2][128][40];
  const int tid = threadIdx.x;
  const int lane = tid & 63;
  const int w = tid >> 6;          // 0..3
  const int wm = w >> 1, wn = w & 1;  // wave grid 2x2
  const int l15 = lane & 15, l4 = lane >> 4;

  const int m0 = blockIdx.y * 128;
  const int bl = blockIdx.x >> 7;            // group-local batch
  const int t0 = (blockIdx.x & 127) << 7;    // 128-wide t tile
  const int b = b_off + bl;

  const short* Asrc = Wskp + (size_t)m0 * KZ;
  const short* Bsrc = zg + ((size_t)bl * TT + t0) * KZ;

  // staging: thread handles row r = tid>>1, 16 contiguous shorts at col (tid&1)*16
  const int sr = tid >> 1;
  const int sc = (tid & 1) * 16;

  f32x4 acc[4][4];
#pragma unroll
  for (int i = 0; i < 4; i++)
#pragma unroll
    for (int j = 0; j < 4; j++) acc[i][j] = (f32x4)0.f;

  bf8 ra0, ra1, rb0, rb1;
  // prologue: load k=0, write buf 0
  ra0 = *(const bf8*)(Asrc + (size_t)sr * KZ + sc);
  ra1 = *(const bf8*)(Asrc + (size_t)sr * KZ + sc + 8);
  rb0 = *(const bf8*)(Bsrc + (size_t)sr * KZ + sc);
  rb1 = *(const bf8*)(Bsrc + (size_t)sr * KZ + sc + 8);
  *(bf8*)&At[0][sr][sc] = ra0; *(bf8*)&At[0][sr][sc + 8] = ra1;
  *(bf8*)&Bt[0][sr][sc] = rb0; *(bf8*)&Bt[0][sr][sc + 8] = rb1;
  __syncthreads();

  for (int ks = 0; ks < 64; ks++) {
    const int cur = ks & 1;
    if (ks < 63) {
      const int k1 = (ks + 1) * 32;
      ra0 = *(const bf8*)(Asrc + (size_t)sr * KZ + k1 + sc);
      ra1 = *(const bf8*)(Asrc + (size_t)sr * KZ + k1 + sc + 8);
      rb0 = *(const bf8*)(Bsrc + (size_t)sr * KZ + k1 + sc);
      rb1 = *(const bf8*)(Bsrc + (size_t)sr * KZ + k1 + sc + 8);
    }
    // compute on cur
    bf8 Af[4], Bf[4];
#pragma unroll
    for (int mt = 0; mt < 4; mt++)
      Af[mt] = *(const bf8*)&At[cur][wm * 64 + mt * 16 + l15][l4 * 8];
#pragma unroll
    for (int nt = 0; nt < 4; nt++)
      Bf[nt] = *(const bf8*)&Bt[cur][wn * 64 + nt * 16 + l15][l4 * 8];
#pragma unroll
    for (int mt = 0; mt < 4; mt++)
#pragma unroll
      for (int nt = 0; nt < 4; nt++)
        acc[mt][nt] = __builtin_amdgcn_mfma_f32_16x16x32_bf16(Af[mt], Bf[nt], acc[mt][nt], 0, 0, 0);
    if (ks < 63) {
      __syncthreads();
      *(bf8*)&At[cur ^ 1][sr][sc] = ra0; *(bf8*)&At[cur ^ 1][sr][sc + 8] = ra1;
      *(bf8*)&Bt[cur ^ 1][sr][sc] = rb0; *(bf8*)&Bt[cur ^ 1][sr][sc + 8] = rb1;
      __syncthreads();
    }
  }

  // epilogue: h = relu(acc + bsum) -> out[b][m][t] (f32)
#pragma unroll
  for (int mt = 0; mt < 4; mt++) {
    const int m = m0 + wm * 64 + mt * 16 + l4 * 4;
#pragma unroll
    for (int nt = 0; nt < 4; nt++) {
      const int t = t0 + wn * 64 + nt * 16 + l15;
#pragma unroll
      for (int r = 0; r < 4; r++) {
        float h = fmaxf(acc[mt][nt][r] + bsum[m + r], 0.f);
        out[((size_t)b * NQ + m + r) * TT + t] = h;
      }
    }
  }
}

// ====== k_headW: read h overlay -> W1(+relu) -> W2 -> out in place. grid (TT/64, 8), 256 thr ======
__global__ __launch_bounds__(256) void k_headW(
    float* out, const short* __restrict__ W1p, const float* __restrict__ b1,
    const short* __restrict__ W2p, const float* __restrict__ b2) {
  __shared__ short hT[NTF][264];
  __shared__ short h2T[NTF][264];
  const int b = blockIdx.y;
  const int t0 = blockIdx.x * NTF;
  const int tid = threadIdx.x;
  const int lane = tid & 63, w = tid >> 6;
  const int l15 = lane & 15, l4 = lane >> 4;
  const float* hb = out + (size_t)b * NQ * TT;

  // stage h (already relu'd f32, channels 0..255 incl zero pad) -> bf16 LDS [t][c]
#pragma unroll 4
  for (int p = 0; p < 64; p++) {
    int c = p * 4 + (tid >> 6);
    float v = hb[(size_t)c * TT + t0 + lane];
    hT[lane][c] = f2bf(v);
  }
  __syncthreads();

  f32x4 acc[4][4];
#pragma unroll
  for (int i = 0; i < 4; i++)
#pragma unroll
    for (int j = 0; j < 4; j++) acc[i][j] = (f32x4)0.f;
#pragma unroll
  for (int kk = 0; kk < 8; kk++) {
    const int k = kk * 32;
    bf8 Bv[4];
#pragma unroll
    for (int nt = 0; nt < 4; nt++) Bv[nt] = *(const bf8*)&hT[nt * 16 + l15][k + l4 * 8];
#pragma unroll
    for (int mt = 0; mt < 4; mt++) {
      bf8 Av = *(const bf8*)(W1p + (size_t)(w * 64 + mt * 16 + l15) * 256 + k + l4 * 8);
#pragma unroll
      for (int nt = 0; nt < 4; nt++)
        acc[mt][nt] = __builtin_amdgcn_mfma_f32_16x16x32_bf16(Av, Bv[nt], acc[mt][nt], 0, 0, 0);
    }
  }
#pragma unroll
  for (int mt = 0; mt < 4; mt++) {
    int mb = w * 64 + mt * 16 + l4 * 4;
#pragma unroll
    for (int nt = 0; nt < 4; nt++) {
      s4 hp;
#pragma unroll
      for (int r = 0; r < 4; r++) hp[r] = f2bf(fmaxf(acc[mt][nt][r] + b1[mb + r], 0.f));
      *(s4*)&h2T[nt * 16 + l15][mb] = hp;
    }
  }
  __syncthreads();

#pragma unroll
  for (int i = 0; i < 4; i++)
#pragma unroll
    for (int j = 0; j < 4; j++) acc[i][j] = (f32x4)0.f;
#pragma unroll
  for (int kk = 0; kk < 8; kk++) {
    const int k = kk * 32;
    bf8 Bv[4];
#pragma unroll
    for (int nt = 0; nt < 4; nt++) Bv[nt] = *(const bf8*)&h2T[nt * 16 + l15][k + l4 * 8];
#pragma unroll
    for (int mt = 0; mt < 4; mt++) {
      bf8 Av = *(const bf8*)(W2p + (size_t)(w * 64 + mt * 16 + l15) * 256 + k + l4 * 8);
#pragma unroll
      for (int nt = 0; nt < 4; nt++)
        acc[mt][nt] = __builtin_amdgcn_mfma_f32_16x16x32_bf16(Av, Bv[nt], acc[mt][nt], 0, 0, 0);
    }
  }
#pragma unroll
  for (int mt = 0; mt < 4; mt++) {
    int q = w * 64 + mt * 16 + l4 * 4;
#pragma unroll
    for (int nt = 0; nt < 4; nt++) {
      int t = t0 + nt * 16 + l15;
#pragma unroll
      for (int r = 0; r < 4; r++)
        out[((size_t)b * NQ + q + r) * TT + t] = acc[mt][nt][r] + b2[q + r];
    }
  }
}

// ================== FALLBACK PATH (round-2, passing; NTF=64, 256 thr) ==================
__global__ __launch_bounds__(256) void k_res_mfma(
    const short* __restrict__ xin, short* __restrict__ xout,
    float* __restrict__ skip,
    const short* __restrict__ Afg, const short* __restrict__ Ars,
    const float* __restrict__ biasp, int layer, int dil, int first) {
  __shared__ short zT[NTF][136];
  const int b = blockIdx.y;
  const int t0 = blockIdx.x * NTF;
  const int tid = threadIdx.x;
  const int lane = tid & 63, w = tid >> 6;
  const int l15 = lane & 15, l4 = lane >> 4;
  const size_t xbase = (size_t)b * TT * CH;

  f32x4 fa[2][4], ga[2][4];
#pragma unroll
  for (int i = 0; i < 2; i++)
#pragma unroll
    for (int j = 0; j < 4; j++) { fa[i][j] = (f32x4)0.f; ga[i][j] = (f32x4)0.f; }

  const short* pBd[4];
  const short* pBc[4];
  bool vld[4];
#pragma unroll
  for (int nt = 0; nt < 4; nt++) {
    int t = t0 + nt * 16 + l15;
    int ts = t - dil;
    vld[nt] = (ts >= 0);
    pBd[nt] = xin + xbase + (size_t)(vld[nt] ? ts : 0) * CH + l4 * 8;
    pBc[nt] = xin + xbase + (size_t)t * CH + l4 * 8;
  }
  const short* pAf[2];
  const short* pAg[2];
#pragma unroll
  for (int mt = 0; mt < 2; mt++) {
    pAf[mt] = Afg + (size_t)(w * 32 + mt * 16 + l15) * 256 + l4 * 8;
    pAg[mt] = Afg + (size_t)(128 + w * 32 + mt * 16 + l15) * 256 + l4 * 8;
  }
  const bf8 zv = (bf8)(short)0;
#pragma unroll
  for (int kk = 0; kk < 8; kk++) {
    const int k = kk * 32;
    bf8 Bv[4];
#pragma unroll
    for (int nt = 0; nt < 4; nt++) {
      if (kk < 4) {
        bf8 v = *(const bf8*)(pBd[nt] + k);
        Bv[nt] = vld[nt] ? v : zv;
      } else {
        Bv[nt] = *(const bf8*)(pBc[nt] + (k - 128));
      }
    }
#pragma unroll
    for (int mt = 0; mt < 2; mt++) {
      bf8 Av = *(const bf8*)(pAf[mt] + k);
      bf8 Gv = *(const bf8*)(pAg[mt] + k);
#pragma unroll
      for (int nt = 0; nt < 4; nt++) {
        fa[mt][nt] = __builtin_amdgcn_mfma_f32_16x16x32_bf16(Av, Bv[nt], fa[mt][nt], 0, 0, 0);
        ga[mt][nt] = __builtin_amdgcn_mfma_f32_16x16x32_bf16(Gv, Bv[nt], ga[mt][nt], 0, 0, 0);
      }
    }
  }

  const float* bf_ = biasp + (size_t)layer * 128;
  const float* bg_ = biasp + 2048 + (size_t)layer * 128;
#pragma unroll
  for (int mt = 0; mt < 2; mt++) {
    int mb = w * 32 + mt * 16 + l4 * 4;
#pragma unroll
    for (int nt = 0; nt < 4; nt++) {
      s4 zp;
#pragma unroll
      for (int r = 0; r < 4; r++) {
        float f = fa[mt][nt][r] + bf_[mb + r];
        float g = ga[mt][nt][r] + bg_[mb + r];
        float th = 1.f - 2.f / (__expf(2.f * f) + 1.f);
        float sg = 1.f / (1.f + __expf(-g));
        zp[r] = f2bf(th * sg);
      }
      *(s4*)&zT[nt * 16 + l15][mb] = zp;
    }
  }
  __syncthreads();

  f32x4 acc[6][4];
#pragma unroll
  for (int i = 0; i < 6; i++)
#pragma unroll
    for (int j = 0; j < 4; j++) acc[i][j] = (f32x4)0.f;
  const short* pA[6];
#pragma unroll
  for (int mt = 0; mt < 6; mt++)
    pA[mt] = Ars + (size_t)(w * 96 + mt * 16 + l15) * 128 + l4 * 8;
#pragma unroll
  for (int kk = 0; kk < 4; kk++) {
    const int k = kk * 32;
    bf8 Bv[4];
#pragma unroll
    for (int nt = 0; nt < 4; nt++) Bv[nt] = *(const bf8*)&zT[nt * 16 + l15][k + l4 * 8];
#pragma unroll
    for (int mt = 0; mt < 6; mt++) {
      bf8 Av = *(const bf8*)(pA[mt] + k);
#pragma unroll
      for (int nt = 0; nt < 4; nt++)
        acc[mt][nt] = __builtin_amdgcn_mfma_f32_16x16x32_bf16(Av, Bv[nt], acc[mt][nt], 0, 0, 0);
    }
  }

  const float* br_ = biasp + 4096 + (size_t)layer * 128;
  const float* bs_ = biasp + 6144 + (size_t)layer * 256;
#pragma unroll
  for (int mt = 0; mt < 6; mt++) {
    int m = w * 96 + mt * 16 + l4 * 4;
#pragma unroll
    for (int nt = 0; nt < 4; nt++) {
      int t = t0 + nt * 16 + l15;
      if (m < 128) {
        s4 xv = *(const s4*)(xin + xbase + (size_t)t * CH + m);
        s4 ov;
#pragma unroll
        for (int r = 0; r < 4; r++)
          ov[r] = f2bf(bf2f(xv[r]) + acc[mt][nt][r] + br_[m + r]);
        *(s4*)(xout + xbase + (size_t)t * CH + m) = ov;
      } else if (m < 128 + SKIPC) {
        int c = m - 128;
        float* sp = skip + ((size_t)b * NQ + c) * TT + t;
#pragma unroll
        for (int r = 0; r < 4; r++) {
          float v = acc[mt][nt][r] + bs_[c + r];
          if (!first) v += sp[(size_t)r * TT];
          sp[(size_t)r * TT] = v;
        }
      }
    }
  }
}

__global__ __launch_bounds__(256) void k_head_mfma(
    const float* skip, const short* __restrict__ W1p, const float* __restrict__ b1,
    const short* __restrict__ W2p, const float* __restrict__ b2, float* out) {
  __shared__ short hT[NTF][264];
  __shared__ short h2T[NTF][264];
  const int b = blockIdx.y;
  const int t0 = blockIdx.x * NTF;
  const int tid = threadIdx.x;
  const int lane = tid & 63, w = tid >> 6;
  const int l15 = lane & 15, l4 = lane >> 4;

  for (int u = tid; u < 256 * 16; u += 256) {
    int c = u >> 4, tq = u & 15;
    if (c < SKIPC) {
      f32x4 v = *(const f32x4*)(skip + ((size_t)b * NQ + c) * TT + t0 + tq * 4);
#pragma unroll
      for (int j = 0; j < 4; j++) hT[tq * 4 + j][c] = f2bf(fmaxf(v[j], 0.f));
    } else {
#pragma unroll
      for (int j = 0; j < 4; j++) hT[tq * 4 + j][c] = 0;
    }
  }
  __syncthreads();

  f32x4 acc[4][4];
#pragma unroll
  for (int i = 0; i < 4; i++)
#pragma unroll
    for (int j = 0; j < 4; j++) acc[i][j] = (f32x4)0.f;
#pragma unroll
  for (int kk = 0; kk < 8; kk++) {
    const int k = kk * 32;
    bf8 Bv[4];
#pragma unroll
    for (int nt = 0; nt < 4; nt++) Bv[nt] = *(const bf8*)&hT[nt * 16 + l15][k + l4 * 8];
#pragma unroll
    for (int mt = 0; mt < 4; mt++) {
      bf8 Av = *(const bf8*)(W1p + (size_t)(w * 64 + mt * 16 + l15) * 256 + k + l4 * 8);
#pragma unroll
      for (int nt = 0; nt < 4; nt++)
        acc[mt][nt] = __builtin_amdgcn_mfma_f32_16x16x32_bf16(Av, Bv[nt], acc[mt][nt], 0, 0, 0);
    }
  }
#pragma unroll
  for (int mt = 0; mt < 4; mt++) {
    int mb = w * 64 + mt * 16 + l4 * 4;
#pragma unroll
    for (int nt = 0; nt < 4; nt++) {
      s4 hp;
#pragma unroll
      for (int r = 0; r < 4; r++) hp[r] = f2bf(fmaxf(acc[mt][nt][r] + b1[mb + r], 0.f));
      *(s4*)&h2T[nt * 16 + l15][mb] = hp;
    }
  }
  __syncthreads();

#pragma unroll
  for (int i = 0; i < 4; i++)
#pragma unroll
    for (int j = 0; j < 4; j++) acc[i][j] = (f32x4)0.f;
#pragma unroll
  for (int kk = 0; kk < 8; kk++) {
    const int k = kk * 32;
    bf8 Bv[4];
#pragma unroll
    for (int nt = 0; nt < 4; nt++) Bv[nt] = *(const bf8*)&h2T[nt * 16 + l15][k + l4 * 8];
#pragma unroll
    for (int mt = 0; mt < 4; mt++) {
      bf8 Av = *(const bf8*)(W2p + (size_t)(w * 64 + mt * 16 + l15) * 256 + k + l4 * 8);
#pragma unroll
      for (int nt = 0; nt < 4; nt++)
        acc[mt][nt] = __builtin_amdgcn_mfma_f32_16x16x32_bf16(Av, Bv[nt], acc[mt][nt], 0, 0, 0);
    }
  }
#pragma unroll
  for (int mt = 0; mt < 4; mt++) {
    int q = w * 64 + mt * 16 + l4 * 4;
#pragma unroll
    for (int nt = 0; nt < 4; nt++) {
      int t = t0 + nt * 16 + l15;
#pragma unroll
      for (int r = 0; r < 4; r++)
        out[((size_t)b * NQ + q + r) * TT + t] = acc[mt][nt][r] + b2[q + r];
    }
  }
}

extern "C" void kernel_launch(void* const* d_in, const int* in_sizes, int n_in,
                              void* d_out, int out_size, void* d_ws, size_t ws_size,
                              hipStream_t stream) {
  const float* wave  = (const float*)d_in[0];
  const float* W_in  = (const float*)d_in[1];
  const float* b_in  = (const float*)d_in[2];
  const float* Wf    = (const float*)d_in[3];
  const float* bf    = (const float*)d_in[4];
  const float* Wg    = (const float*)d_in[5];
  const float* bg    = (const float*)d_in[6];
  const float* Wres  = (const float*)d_in[7];
  const float* bres  = (const float*)d_in[8];
  const float* Wskip = (const float*)d_in[9];
  const float* bskip = (const float*)d_in[10];
  const float* W1    = (const float*)d_in[11];
  const float* b1    = (const float*)d_in[12];
  const float* W2    = (const float*)d_in[13];
  const float* b2    = (const float*)d_in[14];
  float* out = (float*)d_out;

  char* ws = (char*)d_ws;
  short* xA    = (short*)ws;                    // 33,554,432 B
  short* xB    = (short*)(ws + 33554432);       // 33,554,432 B
  short* Afg   = (short*)(ws + 67108864);       //  2,097,152 B
  short* Ars   = (short*)(ws + 69206016);       //  1,572,864 B
  short* W1p   = (short*)(ws + 70778880);       //    131,072 B
  short* W2p   = (short*)(ws + 70909952);       //    131,072 B
  float* biasp = (float*)(ws + 71041024);       //     40,960 B
  short* Wskp  = (short*)(ws + 71081984);       //  1,048,576 B
  float* bsum  = (float*)(ws + 72130560);       //      1,024 B
  short* zg    = (short*)(ws + 72131584);       // nbg * 67,108,864 B
  const size_t BASE = 72131584ull;
  const size_t ZPB  = (size_t)TT * KZ * 2;      // 67,108,864 B per batch

  int nbg = 0;
  if (ws_size > BASE) {
    size_t k = (ws_size - BASE) / ZPB;
    nbg = (int)(k > 8 ? 8 : k);
  }

  k_pack<<<1024, 256, 0, stream>>>(Wf, Wg, Wres, Wskip, W1, W2, bf, bg, bres, bskip,
                                   Afg, Ars, W1p, W2p, biasp, Wskp, bsum,
                                   nbg > 0 ? 1 : 0);
  k_input<<<(NBATCH * TT) / 256, 256, 0, stream>>>(wave, W_in, b_in, xA);

  static const int dils[16] = {1, 2, 4, 8, 16, 32, 64, 128,
                               1, 2, 4, 8, 16, 32, 64, 128};
  if (nbg > 0) {
    for (int g = 0; g < NBATCH; g += nbg) {
      const int rem = (NBATCH - g) < nbg ? (NBATCH - g) : nbg;
      const short* xi = xA;
      short* xo = xB;
      for (int i = 0; i < 16; i++) {
        k_res2<<<dim3(TT / NT2, rem), 256, 0, stream>>>(
            xi, xo, zg, Afg + (size_t)i * 65536, Ars + (size_t)i * 49152,
            biasp, i, dils[i], g);
        short* tmp = (short*)xi; xi = xo; xo = tmp;
      }
      k_skip<<<dim3(rem * (TT / 128), 2), 256, 0, stream>>>(zg, Wskp, bsum, out, g);
    }
    k_headW<<<dim3(TT / NTF, NBATCH), 256, 0, stream>>>(out, W1p, b1, W2p, b2);
  } else {
    const short* xi = xA;
    short* xo = xB;
    for (int i = 0; i < 16; i++) {
      k_res_mfma<<<dim3(TT / NTF, NBATCH), 256, 0, stream>>>(
          xi, xo, out, Afg + (size_t)i * 65536, Ars + (size_t)i * 49152,
          biasp, i, dils[i], i == 0 ? 1 : 0);
      short* tmp = (short*)xi; xi = xo; xo = tmp;
    }
    k_head_mfma<<<dim3(TT / NTF, NBATCH), 256, 0, stream>>>(out, W1p, b1, W2p, b2, out);
  }
}